// Round 1
// baseline (688.823 us; speedup 1.0000x reference)
//
#include <hip/hip_runtime.h>
#include <math.h>

#define B_   4
#define C_   256
#define H_   64
#define W_   64
#define CC_  64
#define K_   7
#define K2_  49
#define EK_  5
#define OE_  196
#define OH_  128
#define OW_  128

// ------------------------------------------------------------------
// Kernel 0: weight re-layouts (one-shot, tiny)
//   wct[c][cc]                 = w_comp[cc][c]            (256x64)
//   wt [c][ky][kx][r][n(49)]   = w_enc[4n+r][c][ky][kx]   (64*25*4*49)
// ------------------------------------------------------------------
__global__ __launch_bounds__(256) void prep_weights(
    const float* __restrict__ w_comp, const float* __restrict__ w_enc,
    float* __restrict__ wct, float* __restrict__ wt) {
  int idx = blockIdx.x * 256 + threadIdx.x;
  if (idx < OE_ * CC_ * EK_ * EK_) {
    int o   = idx / (CC_ * EK_ * EK_);        // 0..195
    int rem = idx % (CC_ * EK_ * EK_);
    int c   = rem / (EK_ * EK_);
    int kk  = rem % (EK_ * EK_);
    int n = o >> 2, r = o & 3;
    wt[((c * 25 + kk) * 4 + r) * 49 + n] = w_enc[idx];
  }
  if (idx < C_ * CC_) {
    int cc = idx / C_;      // 0..63
    int c  = idx % C_;      // 0..255
    wct[c * CC_ + cc] = w_comp[cc * C_ + c];
  }
}

// ------------------------------------------------------------------
// Kernel 1: 1x1 channel compressor.  One block per (b,h) row.
// ------------------------------------------------------------------
__global__ __launch_bounds__(256) void compress_k(
    const float* __restrict__ x, const float* __restrict__ wct,
    const float* __restrict__ b_comp, float* __restrict__ comp) {
  __shared__ float xs[C_][W_];   // 64 KB
  int t  = threadIdx.x;
  int bh = blockIdx.x;           // b*64 + h
  int b = bh >> 6, h = bh & 63;
  const float* xrow = x + (size_t)b * C_ * H_ * W_ + (size_t)h * W_;
  for (int i = 0; i < 64; ++i) {
    int idx = i * 256 + t;
    int c = idx >> 6, w = idx & 63;
    xs[c][w] = xrow[(size_t)c * H_ * W_ + w];
  }
  __syncthreads();
  int w   = t & 63;
  int ccg = __builtin_amdgcn_readfirstlane(t >> 6);   // wave-uniform 0..3
  float acc[16];
  #pragma unroll
  for (int i = 0; i < 16; ++i) acc[i] = 0.f;
  for (int c = 0; c < C_; ++c) {
    float xv = xs[c][w];
    const float* wr = wct + c * CC_ + ccg * 16;       // uniform -> s_load
    #pragma unroll
    for (int i = 0; i < 16; ++i) acc[i] = fmaf(xv, wr[i], acc[i]);
  }
  float* orow = comp + ((size_t)b * CC_ + ccg * 16) * H_ * W_ + h * W_ + w;
  #pragma unroll
  for (int i = 0; i < 16; ++i)
    orow[(size_t)i * H_ * W_] = acc[i] + b_comp[ccg * 16 + i];
}

// ------------------------------------------------------------------
// Kernel 2: 5x5 encoder conv (64 -> 196 ch) + pixel-shuffle + softmax,
// fused.  Block = 8x8 pixel tile.  Thread (p = t&63, og = t>>6) owns the
// full softmax set {channels 4n+og, n=0..48} -> softmax is in-register.
// smax layout: [b][h][w][r(4)][n(49)]
// ------------------------------------------------------------------
__global__ __launch_bounds__(256) void enc_softmax_k(
    const float* __restrict__ comp, const float* __restrict__ wt,
    const float* __restrict__ b_enc, float* __restrict__ smax) {
  __shared__ float cs[CC_][12][12];   // 36.9 KB, halo 2
  int t   = threadIdx.x;
  int blk = blockIdx.x;               // b*64 + ty*8 + tx
  int b = blk >> 6;
  int tile = blk & 63;
  int h0 = (tile >> 3) * 8, w0 = (tile & 7) * 8;
  const float* cb = comp + (size_t)b * CC_ * H_ * W_;
  for (int idx = t; idx < CC_ * 144; idx += 256) {
    int c   = idx / 144;
    int rem = idx - c * 144;
    int yy = rem / 12, xx = rem - yy * 12;
    int gh = h0 - 2 + yy, gw = w0 - 2 + xx;
    float v = 0.f;
    if ((unsigned)gh < H_ && (unsigned)gw < W_)
      v = cb[(size_t)c * H_ * W_ + gh * W_ + gw];
    cs[c][yy][xx] = v;
  }
  __syncthreads();
  int p = t & 63;
  int xx = p & 7, yy = p >> 3;
  int og = __builtin_amdgcn_readfirstlane(t >> 6);    // wave-uniform r
  float acc[49];
  #pragma unroll
  for (int n = 0; n < 49; ++n) acc[n] = b_enc[4 * n + og];
  for (int c = 0; c < CC_; ++c) {
    #pragma unroll
    for (int ky = 0; ky < 5; ++ky) {
      #pragma unroll
      for (int kx = 0; kx < 5; ++kx) {
        float xv = cs[c][yy + ky][xx + kx];
        const float* wr = wt + ((c * 25 + ky * 5 + kx) * 4 + og) * 49;
        #pragma unroll
        for (int n = 0; n < 49; ++n) acc[n] = fmaf(xv, wr[n], acc[n]);
      }
    }
  }
  // softmax over n (in-register)
  float m = acc[0];
  #pragma unroll
  for (int n = 1; n < 49; ++n) m = fmaxf(m, acc[n]);
  float s = 0.f;
  #pragma unroll
  for (int n = 0; n < 49; ++n) { acc[n] = __expf(acc[n] - m); s += acc[n]; }
  float inv = 1.f / s;
  float* so = smax + ((size_t)((b * H_ + h0 + yy) * W_ + w0 + xx)) * OE_ + og * 49;
  #pragma unroll
  for (int n = 0; n < 49; ++n) so[n] = acc[n] * inv;
}

// ------------------------------------------------------------------
// Kernel 3: CARAFE reassembly.
// out[b][c][2h+p][2w+q] = sum_{dy,dx} x[b][c][h-3+dy][w-3+dx] *
//                         smax[b][h][w][2p+q][dy*7+dx]
// Block: one (b,h), 32 channels, 32 w-columns.
// ------------------------------------------------------------------
__global__ __launch_bounds__(256) void carafe_k(
    const float* __restrict__ x, const float* __restrict__ smax,
    float* __restrict__ out) {
  __shared__ float xs[32 * 7 * 40];   // 35.8 KB : 32ch x 7rows x 40cols(pad)
  __shared__ float ss[32 * 197];      // 25.2 KB : 32w x 196 (197-stride pad)
  int t   = threadIdx.x;
  int gid = blockIdx.x;
  int cg  = gid & 7;           // channel group: 32 channels
  int wt2 = (gid >> 3) & 1;    // w half
  int bh  = gid >> 4;          // 0..255
  int b = bh >> 6, h = bh & 63;
  int c0 = cg * 32, w0 = wt2 * 32;

  const float* xb = x + (size_t)b * C_ * H_ * W_;
  for (int idx = t; idx < 32 * 7 * 40; idx += 256) {
    int c   = idx / 280;
    int rem = idx - c * 280;
    int dy = rem / 40, j = rem - dy * 40;
    int gh = h - 3 + dy, gw = w0 - 3 + j;
    float v = 0.f;
    if (j < 38 && (unsigned)gh < H_ && (unsigned)gw < W_)
      v = xb[(size_t)(c0 + c) * H_ * W_ + gh * W_ + gw];
    xs[idx] = v;
  }
  const float* sb = smax + ((size_t)((b * H_ + h) * W_ + w0)) * OE_;
  for (int idx = t; idx < 32 * OE_; idx += 256) {
    int w = idx / OE_, k = idx - w * OE_;
    ss[w * 197 + k] = sb[(size_t)w * OE_ + k];
  }
  __syncthreads();

  int w  = t & 31;
  int tg = t >> 5;             // 0..7 -> 4 channels each
  float acc[4][4];
  #pragma unroll
  for (int i = 0; i < 4; ++i)
    #pragma unroll
    for (int r = 0; r < 4; ++r) acc[i][r] = 0.f;

  #pragma unroll
  for (int dy = 0; dy < 7; ++dy) {
    #pragma unroll
    for (int dx = 0; dx < 7; ++dx) {
      int n = dy * 7 + dx;
      float sv[4];
      #pragma unroll
      for (int r = 0; r < 4; ++r) sv[r] = ss[w * 197 + r * 49 + n];
      #pragma unroll
      for (int ci = 0; ci < 4; ++ci) {
        float xv = xs[(tg * 4 + ci) * 280 + dy * 40 + w + dx];
        #pragma unroll
        for (int r = 0; r < 4; ++r)
          acc[ci][r] = fmaf(xv, sv[r], acc[ci][r]);
      }
    }
  }
  #pragma unroll
  for (int ci = 0; ci < 4; ++ci) {
    int c = c0 + tg * 4 + ci;
    #pragma unroll
    for (int p = 0; p < 2; ++p) {
      float2 v = make_float2(acc[ci][2 * p], acc[ci][2 * p + 1]);
      float* dst = out + ((size_t)(b * C_ + c) * OH_ + (2 * h + p)) * OW_
                   + 2 * (w0 + w);
      *reinterpret_cast<float2*>(dst) = v;
    }
  }
}

// ------------------------------------------------------------------
extern "C" void kernel_launch(void* const* d_in, const int* in_sizes, int n_in,
                              void* d_out, int out_size, void* d_ws, size_t ws_size,
                              hipStream_t stream) {
  const float* x      = (const float*)d_in[0];
  const float* w_comp = (const float*)d_in[1];
  const float* b_comp = (const float*)d_in[2];
  const float* w_enc  = (const float*)d_in[3];
  const float* b_enc  = (const float*)d_in[4];
  float* out = (float*)d_out;

  float* ws   = (float*)d_ws;
  float* comp = ws;                       // 1,048,576 floats
  float* wct  = comp + 1048576;           //    16,384
  float* wt   = wct + 16384;              //   313,600
  float* smax = wt + 313600;              // 3,211,264   (total ~18.3 MB)

  prep_weights<<<1225, 256, 0, stream>>>(w_comp, w_enc, wct, wt);
  compress_k<<<B_ * H_, 256, 0, stream>>>(x, wct, b_comp, comp);
  enc_softmax_k<<<B_ * 64, 256, 0, stream>>>(comp, wt, b_enc, smax);
  carafe_k<<<B_ * H_ * 2 * 8, 256, 0, stream>>>(x, smax, out);
}

// Round 2
// 203.360 us; speedup vs baseline: 3.3872x; 3.3872x over previous
//
#include <hip/hip_runtime.h>
#include <math.h>
#include <stdint.h>

#define B_   4
#define C_   256
#define H_   64
#define W_   64
#define CC_  64
#define OE_  196
#define OH_  128
#define OW_  128

typedef uint32_t u32;
typedef __attribute__((ext_vector_type(8))) short bf16x8;
typedef __attribute__((ext_vector_type(4))) float f32x4;
typedef __attribute__((ext_vector_type(4))) u32 u32x4;

__device__ __forceinline__ unsigned short f2bf(float f) {
  u32 u = __builtin_bit_cast(u32, f);
  u32 r = (u + 0x7FFFu + ((u >> 16) & 1u)) >> 16;   // RNE
  return (unsigned short)r;
}

// ------------------------------------------------------------------
// Kernel 0: weight re-layouts (runs every launch; tiny).
//  wct[c][cc] = w_comp[cc][c]
//  wfrag[ks(50)][mt(14)][lane(64)][j(8)] bf16, fragment-linear for MFMA:
//    o = mt*16 + (lane&15); tap = ks>>1; s = ks&1; c = s*32 + (lane>>4)*8 + j
//    val = (o<196) ? w_enc[o][c][tap/5][tap%5] : 0
// ------------------------------------------------------------------
__global__ __launch_bounds__(256) void prep_weights(
    const float* __restrict__ w_comp, const float* __restrict__ w_enc,
    float* __restrict__ wct, unsigned short* __restrict__ wfrag) {
  int idx = blockIdx.x * 256 + threadIdx.x;
  if (idx < 50 * 14 * 64) {
    int lane = idx & 63;
    int mt   = (idx >> 6) % 14;
    int ks   = idx / (14 * 64);
    int o    = mt * 16 + (lane & 15);
    int tap  = ks >> 1, s = ks & 1;
    int ky   = tap / 5, kx = tap % 5;
    int cb   = s * 32 + (lane >> 4) * 8;
    u32 pk[4];
    #pragma unroll
    for (int p = 0; p < 4; ++p) {
      unsigned short lo = 0, hi = 0;
      if (o < OE_) {
        lo = f2bf(w_enc[((o * CC_ + cb + 2 * p) * 5 + ky) * 5 + kx]);
        hi = f2bf(w_enc[((o * CC_ + cb + 2 * p + 1) * 5 + ky) * 5 + kx]);
      }
      pk[p] = (u32)lo | ((u32)hi << 16);
    }
    *reinterpret_cast<u32x4*>(wfrag + (size_t)idx * 8) =
        *reinterpret_cast<u32x4*>(pk);
  }
  if (idx < C_ * CC_) {
    int cc = idx / C_, c = idx % C_;
    wct[c * CC_ + cc] = w_comp[cc * C_ + c];
  }
}

// ------------------------------------------------------------------
// Kernel 1: 1x1 compressor -> channels-last bf16  comp[b][h][w][cc]
// ------------------------------------------------------------------
__global__ __launch_bounds__(256) void compress_k(
    const float* __restrict__ x, const float* __restrict__ wct,
    const float* __restrict__ b_comp, unsigned short* __restrict__ comp) {
  __shared__ float xs[C_][W_];   // 64 KB
  int t  = threadIdx.x;
  int bh = blockIdx.x;
  int b = bh >> 6, h = bh & 63;
  const float* xrow = x + (size_t)b * C_ * H_ * W_ + (size_t)h * W_;
  for (int i = 0; i < 64; ++i) {
    int idx = i * 256 + t;
    int c = idx >> 6, w = idx & 63;
    xs[c][w] = xrow[(size_t)c * H_ * W_ + w];
  }
  __syncthreads();
  int w   = t & 63;
  int ccg = __builtin_amdgcn_readfirstlane(t >> 6);   // wave-uniform 0..3
  float acc[16];
  #pragma unroll
  for (int i = 0; i < 16; ++i) acc[i] = 0.f;
  for (int c = 0; c < C_; ++c) {
    float xv = xs[c][w];
    const float* wr = wct + c * CC_ + ccg * 16;       // uniform -> s_load
    #pragma unroll
    for (int i = 0; i < 16; ++i) acc[i] = fmaf(xv, wr[i], acc[i]);
  }
  u32 pk[8];
  #pragma unroll
  for (int p = 0; p < 8; ++p) {
    unsigned short lo = f2bf(acc[2 * p]     + b_comp[ccg * 16 + 2 * p]);
    unsigned short hi = f2bf(acc[2 * p + 1] + b_comp[ccg * 16 + 2 * p + 1]);
    pk[p] = (u32)lo | ((u32)hi << 16);
  }
  unsigned short* dst = comp + ((size_t)(bh) * 64 + w) * CC_ + ccg * 16;
  reinterpret_cast<u32x4*>(dst)[0] = *reinterpret_cast<u32x4*>(pk);
  reinterpret_cast<u32x4*>(dst)[1] = *reinterpret_cast<u32x4*>(pk + 4);
}

// ------------------------------------------------------------------
// Kernel 2: encoder 5x5 conv as MFMA GEMM + fused pixel-shuffle softmax.
// Block = one (b,h) row: M=224 (14 mtiles, 196 real), N=64 px, K=1600.
// B operand: LDS tile cs[5 rows][68 cols][64 c] bf16, XOR-swizzled
//            (byte ^= (col&7)<<4) -> taps are shifted views, no im2col.
// A operand: per-kstep 14336B fragment-linear weight block, double-buffered
//            via global_load_lds width=16 (2-phase pipeline).
// Epilogue: logits -> LDS [224][68] f32 -> per-(px,r) 49-way softmax.
// ------------------------------------------------------------------
#define WB_ 14336
#define CSB_ 43520
__global__ __launch_bounds__(256) void enc_mfma_k(
    const unsigned short* __restrict__ comp,
    const unsigned short* __restrict__ wfrag,
    const float* __restrict__ b_enc,
    float* __restrict__ smax) {
  __shared__ __align__(16) char lds[CSB_ + 2 * WB_];   // 72192 B
  char* wbuf0 = lds + CSB_;
  char* wbuf1 = lds + CSB_ + WB_;

  int t = threadIdx.x;
  int bh = blockIdx.x;
  int b = bh >> 6, h = bh & 63;

  // ---- stage B tile (rows h-2..h+2, cols 0..67 with 2-col zero halo) ----
  {
    u32x4 z = {0, 0, 0, 0};
    for (int i = t; i < 160; i += 256) {           // halo cols 0,1,66,67
      int r = i / 32, rem = i & 31, ch = rem >> 3, q = rem & 7;
      int col = (ch < 2) ? ch : 64 + ch;
      int byte = ((r * 68 + col) * 128 + q * 16) ^ ((col & 7) << 4);
      *reinterpret_cast<u32x4*>(lds + byte) = z;
    }
    const unsigned short* cbse = comp + (size_t)b * H_ * W_ * CC_;
    for (int i = t; i < 2560; i += 256) {          // 5 rows x 64 cols x 8 chunks
      int r = i >> 9, rem = i & 511, w = rem >> 3, q = rem & 7;
      int hh = h - 2 + r;
      u32x4 v = {0, 0, 0, 0};
      if ((unsigned)hh < H_)
        v = *reinterpret_cast<const u32x4*>(cbse + ((size_t)hh * W_ + w) * CC_ + q * 8);
      int col = w + 2;
      int byte = ((r * 68 + col) * 128 + q * 16) ^ ((col & 7) << 4);
      *reinterpret_cast<u32x4*>(lds + byte) = v;
    }
  }

  int wv    = __builtin_amdgcn_readfirstlane(t >> 6);
  int lane  = t & 63;
  int nlane = lane & 15, kq = lane >> 4;
  int mtbase = (wv < 2) ? wv * 4 : 3 * wv + 2;   // {0,4,8,11}
  int mtcnt  = (wv < 2) ? 4 : 3;                 // {4,4,3,3}

  // ---- weight staging: wave wv copies chunks {wv, wv+4, ...} of 14 ----
  #define STAGE_W(ks, dstbuf)                                                 \
    {                                                                         \
      const char* _s = (const char*)wfrag + (size_t)(ks) * WB_;               \
      for (int _i = wv; _i < 14; _i += 4)                                     \
        __builtin_amdgcn_global_load_lds(                                     \
            (const __attribute__((address_space(1))) u32*)(_s + _i * 1024 +   \
                                                           lane * 16),        \
            (__attribute__((address_space(3))) u32*)((dstbuf) + _i * 1024),   \
            16, 0, 0);                                                        \
    }

  STAGE_W(0, wbuf0);
  __syncthreads();   // drains vmcnt+lgkm: B tile + wbuf0 ready

  f32x4 acc[4][4];
  #pragma unroll
  for (int mm = 0; mm < 4; ++mm)
    #pragma unroll
    for (int nt = 0; nt < 4; ++nt) acc[mm][nt] = (f32x4){0.f, 0.f, 0.f, 0.f};

  for (int ks = 0; ks < 50; ++ks) {
    char* cur = (ks & 1) ? wbuf1 : wbuf0;
    char* nxt = (ks & 1) ? wbuf0 : wbuf1;
    if (ks + 1 < 50) STAGE_W(ks + 1, nxt);   // issue early, wait at barrier

    int tap = ks >> 1, s = ks & 1;
    int ky = tap / 5, kx = tap % 5;

    bf16x8 bf[4];
    #pragma unroll
    for (int nt = 0; nt < 4; ++nt) {
      int col = nt * 16 + nlane + kx;
      int byte = (((ky * 68 + col) * 64 + s * 32 + kq * 8) * 2) ^ ((col & 7) << 4);
      bf[nt] = *reinterpret_cast<const bf16x8*>(lds + byte);
    }
    #pragma unroll
    for (int mm = 0; mm < 4; ++mm) {
      if (mm < mtcnt) {
        bf16x8 af = *reinterpret_cast<const bf16x8*>(
            cur + ((mtbase + mm) * 64 + lane) * 16);
        #pragma unroll
        for (int nt = 0; nt < 4; ++nt)
          acc[mm][nt] = __builtin_amdgcn_mfma_f32_16x16x32_bf16(
              af, bf[nt], acc[mm][nt], 0, 0, 0);
      }
    }
    __syncthreads();   // next wbuf ready; all waves done with cur
  }

  // ---- epilogue: logits to LDS [224][68] f32, then softmax ----
  float* lg = (float*)lds;
  #pragma unroll
  for (int mm = 0; mm < 4; ++mm) {
    if (mm < mtcnt) {
      #pragma unroll
      for (int nt = 0; nt < 4; ++nt) {
        #pragma unroll
        for (int r = 0; r < 4; ++r) {
          int m  = (mtbase + mm) * 16 + kq * 4 + r;
          int px = nt * 16 + nlane;
          lg[m * 68 + px] = acc[mm][nt][r] + (m < OE_ ? b_enc[m] : 0.f);
        }
      }
    }
  }
  __syncthreads();

  int px = t & 63, rr = t >> 6;
  float v[49];
  float mx = -1e30f;
  #pragma unroll
  for (int n = 0; n < 49; ++n) {
    v[n] = lg[(4 * n + rr) * 68 + px];
    mx = fmaxf(mx, v[n]);
  }
  float sum = 0.f;
  #pragma unroll
  for (int n = 0; n < 49; ++n) { v[n] = __expf(v[n] - mx); sum += v[n]; }
  float inv = 1.f / sum;
  float* so = smax + ((size_t)bh * 64 + px) * OE_ + rr * 49;
  #pragma unroll
  for (int n = 0; n < 49; ++n) so[n] = v[n] * inv;
}

// ------------------------------------------------------------------
// Kernel 3: CARAFE reassembly (unchanged from R1).
// ------------------------------------------------------------------
__global__ __launch_bounds__(256) void carafe_k(
    const float* __restrict__ x, const float* __restrict__ smax,
    float* __restrict__ out) {
  __shared__ float xs[32 * 7 * 40];
  __shared__ float ss[32 * 197];
  int t   = threadIdx.x;
  int gid = blockIdx.x;
  int cg  = gid & 7;
  int wt2 = (gid >> 3) & 1;
  int bh  = gid >> 4;
  int b = bh >> 6, h = bh & 63;
  int c0 = cg * 32, w0 = wt2 * 32;

  const float* xb = x + (size_t)b * C_ * H_ * W_;
  for (int idx = t; idx < 32 * 7 * 40; idx += 256) {
    int c   = idx / 280;
    int rem = idx - c * 280;
    int dy = rem / 40, j = rem - dy * 40;
    int gh = h - 3 + dy, gw = w0 - 3 + j;
    float v = 0.f;
    if (j < 38 && (unsigned)gh < H_ && (unsigned)gw < W_)
      v = xb[(size_t)(c0 + c) * H_ * W_ + gh * W_ + gw];
    xs[idx] = v;
  }
  const float* sb = smax + ((size_t)((b * H_ + h) * W_ + w0)) * OE_;
  for (int idx = t; idx < 32 * OE_; idx += 256) {
    int w = idx / OE_, k = idx - w * OE_;
    ss[w * 197 + k] = sb[(size_t)w * OE_ + k];
  }
  __syncthreads();

  int w  = t & 31;
  int tg = t >> 5;
  float acc[4][4];
  #pragma unroll
  for (int i = 0; i < 4; ++i)
    #pragma unroll
    for (int r = 0; r < 4; ++r) acc[i][r] = 0.f;

  #pragma unroll
  for (int dy = 0; dy < 7; ++dy) {
    #pragma unroll
    for (int dx = 0; dx < 7; ++dx) {
      int n = dy * 7 + dx;
      float sv[4];
      #pragma unroll
      for (int r = 0; r < 4; ++r) sv[r] = ss[w * 197 + r * 49 + n];
      #pragma unroll
      for (int ci = 0; ci < 4; ++ci) {
        float xv = xs[(tg * 4 + ci) * 280 + dy * 40 + w + dx];
        #pragma unroll
        for (int r = 0; r < 4; ++r)
          acc[ci][r] = fmaf(xv, sv[r], acc[ci][r]);
      }
    }
  }
  #pragma unroll
  for (int ci = 0; ci < 4; ++ci) {
    int c = c0 + tg * 4 + ci;
    #pragma unroll
    for (int p = 0; p < 2; ++p) {
      float2 v = make_float2(acc[ci][2 * p], acc[ci][2 * p + 1]);
      float* dst = out + ((size_t)(b * C_ + c) * OH_ + (2 * h + p)) * OW_
                   + 2 * (w0 + w);
      *reinterpret_cast<float2*>(dst) = v;
    }
  }
}

// ------------------------------------------------------------------
extern "C" void kernel_launch(void* const* d_in, const int* in_sizes, int n_in,
                              void* d_out, int out_size, void* d_ws, size_t ws_size,
                              hipStream_t stream) {
  const float* x      = (const float*)d_in[0];
  const float* w_comp = (const float*)d_in[1];
  const float* b_comp = (const float*)d_in[2];
  const float* w_enc  = (const float*)d_in[3];
  const float* b_enc  = (const float*)d_in[4];
  float* out = (float*)d_out;

  float* ws = (float*)d_ws;
  float* smax = ws;                                        // 3,211,264 f32
  float* wct  = ws + 3211264;                              //    16,384 f32
  unsigned short* wfrag = (unsigned short*)(wct + 16384);  //   358,400 bf16
  unsigned short* comp  = wfrag + 358400;                  // 1,048,576 bf16

  prep_weights<<<175, 256, 0, stream>>>(w_comp, w_enc, wct, wfrag);
  compress_k<<<B_ * H_, 256, 0, stream>>>(x, wct, b_comp, comp);
  enc_mfma_k<<<B_ * H_, 256, 0, stream>>>(comp, wfrag, b_enc, smax);
  carafe_k<<<B_ * H_ * 2 * 8, 256, 0, stream>>>(x, smax, out);
}

// Round 3
// 156.868 us; speedup vs baseline: 4.3911x; 1.2964x over previous
//
#include <hip/hip_runtime.h>
#include <math.h>
#include <stdint.h>

#define B_   4
#define C_   256
#define H_   64
#define W_   64
#define CC_  64
#define OE_  196
#define OH_  128
#define OW_  128

typedef uint32_t u32;
typedef __attribute__((ext_vector_type(8))) short bf16x8;
typedef __attribute__((ext_vector_type(4))) float f32x4;
typedef __attribute__((ext_vector_type(4))) u32 u32x4;

__device__ __forceinline__ unsigned short f2bf(float f) {
  u32 u = __builtin_bit_cast(u32, f);
  u32 r = (u + 0x7FFFu + ((u >> 16) & 1u)) >> 16;   // RNE
  return (unsigned short)r;
}

// ------------------------------------------------------------------
// Kernel 0: weight re-layouts (tiny).
// ------------------------------------------------------------------
__global__ __launch_bounds__(256) void prep_weights(
    const float* __restrict__ w_comp, const float* __restrict__ w_enc,
    float* __restrict__ wct, unsigned short* __restrict__ wfrag) {
  int idx = blockIdx.x * 256 + threadIdx.x;
  if (idx < 50 * 14 * 64) {
    int lane = idx & 63;
    int mt   = (idx >> 6) % 14;
    int ks   = idx / (14 * 64);
    int o    = mt * 16 + (lane & 15);
    int tap  = ks >> 1, s = ks & 1;
    int ky   = tap / 5, kx = tap % 5;
    int cb   = s * 32 + (lane >> 4) * 8;
    u32 pk[4];
    #pragma unroll
    for (int p = 0; p < 4; ++p) {
      unsigned short lo = 0, hi = 0;
      if (o < OE_) {
        lo = f2bf(w_enc[((o * CC_ + cb + 2 * p) * 5 + ky) * 5 + kx]);
        hi = f2bf(w_enc[((o * CC_ + cb + 2 * p + 1) * 5 + ky) * 5 + kx]);
      }
      pk[p] = (u32)lo | ((u32)hi << 16);
    }
    *reinterpret_cast<u32x4*>(wfrag + (size_t)idx * 8) =
        *reinterpret_cast<u32x4*>(pk);
  }
  if (idx < C_ * CC_) {
    int cc = idx / C_, c = idx % C_;
    wct[c * CC_ + cc] = w_comp[cc * C_ + c];
  }
}

// ------------------------------------------------------------------
// Kernel 1: 1x1 compressor -> bf16 comp[b][h][w][cc]  AND
//           channels-last fp32 transpose xt[b][h][w][c] for carafe.
// ------------------------------------------------------------------
__global__ __launch_bounds__(256) void compress_k(
    const float* __restrict__ x, const float* __restrict__ wct,
    const float* __restrict__ b_comp, unsigned short* __restrict__ comp,
    float* __restrict__ xt) {
  __shared__ float xs[C_][68];   // 69.6 KB, pad 68 for bank spread
  int t  = threadIdx.x;
  int bh = blockIdx.x;
  int b = bh >> 6, h = bh & 63;
  const float* xrow = x + (size_t)b * C_ * H_ * W_ + (size_t)h * W_;
  #pragma unroll
  for (int i = 0; i < 16; ++i) {           // 4096 float4 loads
    int idx = i * 256 + t;
    int c = idx >> 4, wq = idx & 15;
    f32x4 v = *reinterpret_cast<const f32x4*>(xrow + (size_t)c * H_ * W_ + wq * 4);
    *reinterpret_cast<f32x4*>(&xs[c][wq * 4]) = v;
  }
  __syncthreads();

  // --- xt write: lane w, loop over channel chunks (write-combined) ---
  {
    int w = t & 63, cq = t >> 6;
    float* dst = xt + ((size_t)bh * 64 + w) * C_;
    #pragma unroll
    for (int i = 0; i < 16; ++i) {
      int c = (cq * 16 + i) * 4;
      f32x4 v = {xs[c][w], xs[c + 1][w], xs[c + 2][w], xs[c + 3][w]};
      *reinterpret_cast<f32x4*>(dst + c) = v;
    }
  }

  // --- 1x1 conv ---
  int w   = t & 63;
  int ccg = __builtin_amdgcn_readfirstlane(t >> 6);   // wave-uniform 0..3
  float acc[16];
  #pragma unroll
  for (int i = 0; i < 16; ++i) acc[i] = 0.f;
  for (int c = 0; c < C_; ++c) {
    float xv = xs[c][w];
    const float* wr = wct + c * CC_ + ccg * 16;       // uniform -> s_load
    #pragma unroll
    for (int i = 0; i < 16; ++i) acc[i] = fmaf(xv, wr[i], acc[i]);
  }
  u32 pk[8];
  #pragma unroll
  for (int p = 0; p < 8; ++p) {
    unsigned short lo = f2bf(acc[2 * p]     + b_comp[ccg * 16 + 2 * p]);
    unsigned short hi = f2bf(acc[2 * p + 1] + b_comp[ccg * 16 + 2 * p + 1]);
    pk[p] = (u32)lo | ((u32)hi << 16);
  }
  unsigned short* dst = comp + ((size_t)bh * 64 + w) * CC_ + ccg * 16;
  reinterpret_cast<u32x4*>(dst)[0] = *reinterpret_cast<u32x4*>(pk);
  reinterpret_cast<u32x4*>(dst)[1] = *reinterpret_cast<u32x4*>(pk + 4);
}

// ------------------------------------------------------------------
// Kernel 2: encoder 5x5 conv as MFMA GEMM + fused softmax.
// smax layout now [pixel][n(49)][r(4)] for carafe b128 reads.
// ------------------------------------------------------------------
#define WB_ 14336
#define CSB_ 43520
__global__ __launch_bounds__(256) void enc_mfma_k(
    const unsigned short* __restrict__ comp,
    const unsigned short* __restrict__ wfrag,
    const float* __restrict__ b_enc,
    float* __restrict__ smax) {
  __shared__ __align__(16) char lds[CSB_ + 2 * WB_];   // 72192 B
  char* wbuf0 = lds + CSB_;
  char* wbuf1 = lds + CSB_ + WB_;

  int t = threadIdx.x;
  int bh = blockIdx.x;
  int b = bh >> 6, h = bh & 63;

  {
    u32x4 z = {0, 0, 0, 0};
    for (int i = t; i < 160; i += 256) {
      int r = i / 32, rem = i & 31, ch = rem >> 3, q = rem & 7;
      int col = (ch < 2) ? ch : 64 + ch;
      int byte = ((r * 68 + col) * 128 + q * 16) ^ ((col & 7) << 4);
      *reinterpret_cast<u32x4*>(lds + byte) = z;
    }
    const unsigned short* cbse = comp + (size_t)b * H_ * W_ * CC_;
    for (int i = t; i < 2560; i += 256) {
      int r = i >> 9, rem = i & 511, w = rem >> 3, q = rem & 7;
      int hh = h - 2 + r;
      u32x4 v = {0, 0, 0, 0};
      if ((unsigned)hh < H_)
        v = *reinterpret_cast<const u32x4*>(cbse + ((size_t)hh * W_ + w) * CC_ + q * 8);
      int col = w + 2;
      int byte = ((r * 68 + col) * 128 + q * 16) ^ ((col & 7) << 4);
      *reinterpret_cast<u32x4*>(lds + byte) = v;
    }
  }

  int wv    = __builtin_amdgcn_readfirstlane(t >> 6);
  int lane  = t & 63;
  int nlane = lane & 15, kq = lane >> 4;
  int mtbase = (wv < 2) ? wv * 4 : 3 * wv + 2;   // {0,4,8,11}
  int mtcnt  = (wv < 2) ? 4 : 3;

  #define STAGE_W(ks, dstbuf)                                                 \
    {                                                                         \
      const char* _s = (const char*)wfrag + (size_t)(ks) * WB_;               \
      for (int _i = wv; _i < 14; _i += 4)                                     \
        __builtin_amdgcn_global_load_lds(                                     \
            (const __attribute__((address_space(1))) u32*)(_s + _i * 1024 +   \
                                                           lane * 16),        \
            (__attribute__((address_space(3))) u32*)((dstbuf) + _i * 1024),   \
            16, 0, 0);                                                        \
    }

  STAGE_W(0, wbuf0);
  __syncthreads();

  f32x4 acc[4][4];
  #pragma unroll
  for (int mm = 0; mm < 4; ++mm)
    #pragma unroll
    for (int nt = 0; nt < 4; ++nt) acc[mm][nt] = (f32x4){0.f, 0.f, 0.f, 0.f};

  for (int ks = 0; ks < 50; ++ks) {
    char* cur = (ks & 1) ? wbuf1 : wbuf0;
    char* nxt = (ks & 1) ? wbuf0 : wbuf1;
    if (ks + 1 < 50) STAGE_W(ks + 1, nxt);

    int tap = ks >> 1, s = ks & 1;
    int ky = tap / 5, kx = tap % 5;

    bf16x8 bf[4];
    #pragma unroll
    for (int nt = 0; nt < 4; ++nt) {
      int col = nt * 16 + nlane + kx;
      int byte = (((ky * 68 + col) * 64 + s * 32 + kq * 8) * 2) ^ ((col & 7) << 4);
      bf[nt] = *reinterpret_cast<const bf16x8*>(lds + byte);
    }
    #pragma unroll
    for (int mm = 0; mm < 4; ++mm) {
      if (mm < mtcnt) {
        bf16x8 af = *reinterpret_cast<const bf16x8*>(
            cur + ((mtbase + mm) * 64 + lane) * 16);
        #pragma unroll
        for (int nt = 0; nt < 4; ++nt)
          acc[mm][nt] = __builtin_amdgcn_mfma_f32_16x16x32_bf16(
              af, bf[nt], acc[mm][nt], 0, 0, 0);
      }
    }
    __syncthreads();
  }

  float* lg = (float*)lds;
  #pragma unroll
  for (int mm = 0; mm < 4; ++mm) {
    if (mm < mtcnt) {
      #pragma unroll
      for (int nt = 0; nt < 4; ++nt) {
        #pragma unroll
        for (int r = 0; r < 4; ++r) {
          int m  = (mtbase + mm) * 16 + kq * 4 + r;
          int px = nt * 16 + nlane;
          lg[m * 68 + px] = acc[mm][nt][r] + (m < OE_ ? b_enc[m] : 0.f);
        }
      }
    }
  }
  __syncthreads();

  int px = t & 63, rr = t >> 6;
  float v[49];
  float mx = -1e30f;
  #pragma unroll
  for (int n = 0; n < 49; ++n) {
    v[n] = lg[(4 * n + rr) * 68 + px];
    mx = fmaxf(mx, v[n]);
  }
  float sum = 0.f;
  #pragma unroll
  for (int n = 0; n < 49; ++n) { v[n] = __expf(v[n] - mx); sum += v[n]; }
  float inv = 1.f / sum;
  float* so = smax + ((size_t)bh * 64 + px) * OE_;
  #pragma unroll
  for (int n = 0; n < 49; ++n) so[n * 4 + rr] = v[n] * inv;   // [n][r] layout
}

// ------------------------------------------------------------------
// Kernel 3: CARAFE v2 — b128 everything.
// Block: 32 channels x 32 w.  xs[7][38][36-pad] channels-last fp32,
// ss[32][228-pad] = [w][n*4+r].  Per tap: 2 x ds_read_b128 + 16 FMA.
// ------------------------------------------------------------------
__global__ __launch_bounds__(256) void carafe_k(
    const float* __restrict__ xt, const float* __restrict__ smax,
    float* __restrict__ out) {
  __shared__ __align__(16) float lds[7 * 38 * 36 + 32 * 228];   // 67,488 B
  float* xs = lds;                 // [dy][j][c] stride 36
  float* ssm = lds + 7 * 38 * 36;  // [w][228]

  int t   = threadIdx.x;
  int gid = blockIdx.x;
  int cg  = gid & 7;
  int wh  = (gid >> 3) & 1;
  int bh  = gid >> 4;
  int b = bh >> 6, h = bh & 63;
  int c0 = cg * 32, w0 = wh * 32;

  // ---- stage x tile: 7 rows x 38 cols x 32 ch (f32x4 per 4 ch) ----
  for (int idx = t; idx < 2128; idx += 256) {
    int dy = idx / 304, rem = idx % 304;
    int j = rem >> 3, q = rem & 7;
    int gh = h - 3 + dy, gw = w0 - 3 + j;
    f32x4 v = {0.f, 0.f, 0.f, 0.f};
    if ((unsigned)gh < H_ && (unsigned)gw < W_)
      v = *reinterpret_cast<const f32x4*>(
          xt + (((size_t)(b * 64 + gh)) * 64 + gw) * C_ + c0 + q * 4);
    *reinterpret_cast<f32x4*>(xs + (dy * 38 + j) * 36 + q * 4) = v;
  }
  // ---- stage smax tile: 32 w x 49 taps x 4 r ----
  for (int idx = t; idx < 1568; idx += 256) {
    int w = idx / 49, q = idx % 49;
    f32x4 v = *reinterpret_cast<const f32x4*>(
        smax + ((size_t)bh * 64 + w0 + w) * OE_ + q * 4);
    *reinterpret_cast<f32x4*>(ssm + w * 228 + q * 4) = v;
  }
  __syncthreads();

  int w = t & 31;
  int coff = (t >> 5) * 4;
  f32x4 acc[4];   // acc[ci] = {r0,r1,r2,r3}
  #pragma unroll
  for (int ci = 0; ci < 4; ++ci) acc[ci] = (f32x4){0.f, 0.f, 0.f, 0.f};

  #pragma unroll
  for (int dy = 0; dy < 7; ++dy) {
    #pragma unroll
    for (int dx = 0; dx < 7; ++dx) {
      int n = dy * 7 + dx;
      f32x4 sv = *reinterpret_cast<const f32x4*>(ssm + w * 228 + n * 4);
      f32x4 xv = *reinterpret_cast<const f32x4*>(
          xs + (dy * 38 + w + dx) * 36 + coff);
      #pragma unroll
      for (int ci = 0; ci < 4; ++ci) {
        acc[ci][0] = fmaf(xv[ci], sv[0], acc[ci][0]);
        acc[ci][1] = fmaf(xv[ci], sv[1], acc[ci][1]);
        acc[ci][2] = fmaf(xv[ci], sv[2], acc[ci][2]);
        acc[ci][3] = fmaf(xv[ci], sv[3], acc[ci][3]);
      }
    }
  }
  #pragma unroll
  for (int ci = 0; ci < 4; ++ci) {
    int c = c0 + coff + ci;
    float* base = out + ((size_t)(b * C_ + c) * OH_ + 2 * h) * OW_ + 2 * (w0 + w);
    *reinterpret_cast<float2*>(base)       = make_float2(acc[ci][0], acc[ci][1]);
    *reinterpret_cast<float2*>(base + OW_) = make_float2(acc[ci][2], acc[ci][3]);
  }
}

// ------------------------------------------------------------------
extern "C" void kernel_launch(void* const* d_in, const int* in_sizes, int n_in,
                              void* d_out, int out_size, void* d_ws, size_t ws_size,
                              hipStream_t stream) {
  const float* x      = (const float*)d_in[0];
  const float* w_comp = (const float*)d_in[1];
  const float* b_comp = (const float*)d_in[2];
  const float* w_enc  = (const float*)d_in[3];
  const float* b_enc  = (const float*)d_in[4];
  float* out = (float*)d_out;

  float* ws = (float*)d_ws;
  float* smax = ws;                                        // 3,211,264 f32
  float* wct  = ws + 3211264;                              //    16,384 f32
  unsigned short* wfrag = (unsigned short*)(wct + 16384);  //   358,400 bf16
  unsigned short* comp  = wfrag + 358400;                  // 1,048,576 bf16
  float* xt = (float*)(comp + 1048576);                    // 4,194,304 f32 (~32.5MB total)

  prep_weights<<<175, 256, 0, stream>>>(w_comp, w_enc, wct, wfrag);
  compress_k<<<B_ * H_, 256, 0, stream>>>(x, wct, b_comp, comp, xt);
  enc_mfma_k<<<B_ * H_, 256, 0, stream>>>(comp, wfrag, b_enc, smax);
  carafe_k<<<B_ * H_ * 2 * 8, 256, 0, stream>>>(xt, smax, out);
}